// Round 11
// baseline (324.146 us; speedup 1.0000x reference)
//
#include <hip/hip_runtime.h>

// Problem constants
#define BB 8
#define NN 4096
#define CC 128
#define RR 16
#define EE 65536
#define NNODES 32768
#define NEDGES 524288
#define BCAP   60                // per-dst bucket capacity (Poisson16: P(ovf)~1e-11)
#define LDB    136               // LDS row stride (shorts): 272B, 16B-aligned, 2-way-conflict-free

typedef unsigned short ushort_t;
typedef short bf16x8 __attribute__((ext_vector_type(8)));
typedef float f32x4 __attribute__((ext_vector_type(4)));

__device__ __forceinline__ unsigned short f2b(float f) {
    unsigned u = __builtin_bit_cast(unsigned, f);
    unsigned r = (u + 0x7fffu + ((u >> 16) & 1u)) >> 16;   // RNE
    return (unsigned short)r;
}
__device__ __forceinline__ float b2f(unsigned short s) {
    return __builtin_bit_cast(float, (unsigned)s << 16);
}
__device__ __forceinline__ float ldf(const void* p, int j, int isbf) {
    return isbf ? b2f(((const ushort_t*)p)[j]) : ((const float*)p)[j];
}
__device__ __forceinline__ int ldi(const int* p, int j, int is64) {
    return p[j << is64];
}

// wave-parallel float-dtype probe: fp32 mantissa noise shows huge bf16 "exponent"
__device__ __forceinline__ int probe_isbf(const ushort_t* xf) {
    int t = threadIdx.x & 63;
    int bad = 0;
    for (int j = t; j < 512; j += 64) {
        unsigned e = (xf[j] >> 7) & 0xffu;
        if (e >= 160u) bad = 1;
    }
    return __ballot(bad) == 0ull;
}

// ---------- pe_k: fused edge-bucketing + casts + flags (one dispatch) ----------
// [0,2048): edge append (long pole, starts first) | [2048,4096): cast x->Xb
// [4096,5184): weights->WT | 5184: flags.  dcnt pre-zeroed by hipMemsetAsync.
__global__ __launch_bounds__(256) void pe_k(const void* __restrict__ x,
                                            const void* __restrict__ relw,
                                            const void* __restrict__ rootw,
                                            const int* __restrict__ ei,
                                            const int* __restrict__ et,
                                            ushort_t* __restrict__ Xb,
                                            ushort_t* __restrict__ WT,
                                            int* __restrict__ dcnt,
                                            int* __restrict__ bucket,
                                            int* __restrict__ flags) {
    int bx = blockIdx.x, t = threadIdx.x;
    if (bx < 2048) {                       // ---- edge path ----
        __shared__ int sw64i, sw64t;
        if (t < 64) {
            int a = (t < 16) ? ei[2 * t + 1] : 0;
            int b = (t < 16) ? et[2 * t + 1] : 0;
            unsigned long long ma = __ballot(a != 0);
            unsigned long long mb = __ballot(b != 0);
            if (t == 0) { sw64i = (ma == 0ull); sw64t = (mb == 0ull); }
        }
        __syncthreads();
        int w64i = sw64i, w64t = sw64t;
        int tid = bx * 256 + t;            // < NEDGES
        int b = tid >> 16, e = tid & 65535;
        int src = ldi(ei, (b * 2) * EE + e, w64i);
        int dst = ldi(ei, (b * 2 + 1) * EE + e, w64i);
        int r = ldi(et, tid, w64t);
        int gd = (b << 12) + dst;
        int pos = atomicAdd(&dcnt[gd], 1);
        if (pos < BCAP)
            bucket[gd * BCAP + pos] = (((b << 12) + src) << 4) | r;
    } else if (bx < 4096) {                // ---- cast_x: uint4 group per thread ----
        int isbf = probe_isbf((const ushort_t*)x);
        int tid = (bx - 2048) * 256 + t;   // < 524288
        if (isbf) {
            ((uint4*)Xb)[tid] = ((const uint4*)x)[tid];
        } else {
            const float4* xf = (const float4*)x;
            float4 a = xf[2 * tid], b = xf[2 * tid + 1];
            ushort4 o0, o1;
            o0.x = f2b(a.x); o0.y = f2b(a.y); o0.z = f2b(a.z); o0.w = f2b(a.w);
            o1.x = f2b(b.x); o1.y = f2b(b.y); o1.z = f2b(b.z); o1.w = f2b(b.w);
            ((ushort4*)Xb)[2 * tid] = o0; ((ushort4*)Xb)[2 * tid + 1] = o1;
        }
    } else if (bx < 5184) {                // ---- cast_w: WT[nglob][k] = Wall[k][nglob] ----
        int isbf = probe_isbf((const ushort_t*)x);
        int tid = (bx - 4096) * 256 + t;   // < 278528
        int nglob = tid >> 7, k = tid & 127;
        int jb = nglob >> 7, n = nglob & 127;
        float v = (jb == 0) ? ldf(rootw, k * 128 + n, isbf)
                            : ldf(relw, ((jb - 1) << 14) + k * 128 + n, isbf);
        WT[tid] = f2b(v);
    } else {                               // ---- flags ----
        if (t < 64) {
            int isbf = probe_isbf((const ushort_t*)x);
            if (t == 0) flags[0] = isbf;
        }
    }
}

// ---------- rgcn_k: fused means + MFMA GEMM + score epilogue ----------
// 256 blocks x 128 nodes. Per rel-block jb: A-tile = x rows (jb=0) or on-the-fly
// per-(node,rel) means gathered from L2-resident Xb (8 MB); B-tile = W_jb^T.
// acc covers the full 128-col output; epilogue does bias+relu+linw reduction.
__global__ __launch_bounds__(256, 1) void rgcn_k(const ushort_t* __restrict__ Xb,
                                                 const ushort_t* __restrict__ WT,
                                                 const int* __restrict__ dcnt,
                                                 const int* __restrict__ bucket,
                                                 const void* __restrict__ bias,
                                                 const void* __restrict__ linw,
                                                 const void* __restrict__ linb,
                                                 void* __restrict__ out,
                                                 const int* __restrict__ flags) {
    __shared__ ushort_t As[128][LDB];      // 34,816 B
    __shared__ ushort_t Bs[128][LDB];      // 34,816 B
    __shared__ int bkc[128][BCAP];         // 30,720 B
    __shared__ int ncs[128];
    __shared__ float scorebuf[128];
    int t = threadIdx.x;
    int m0 = blockIdx.x * 128;
    int isbf = flags[0];
    int node2 = t >> 1, half = t & 1;      // 2 threads per node; feature halves

    if (t < 128) scorebuf[t] = 0.f;
    if (half == 0) {
        int nc = dcnt[m0 + node2];
        ncs[node2] = (nc > BCAP) ? BCAP : nc;
    }
    __syncthreads();
    {
        int nc = ncs[node2];
        const int* bk = bucket + (size_t)(m0 + node2) * BCAP;
        for (int j = half; j < nc; j += 2) bkc[node2][j] = bk[j];
    }
    __syncthreads();

    int wave = t >> 6, lane = t & 63, lrow = lane & 15, lq = lane >> 4;
    int wm = (wave >> 1) * 64, wn = (wave & 1) * 64;
    f32x4 acc[4][4] = {};

    for (int jb = 0; jb < 17; ++jb) {
        // stage B = W_jb^T (128x128): 2048 uint4 chunks, 8/thread
        #pragma unroll
        for (int i = 0; i < 8; ++i) {
            int c = t + i * 256;
            int row = c >> 4, c16 = c & 15;
            uint4 vb = *(const uint4*)(WT + ((size_t)(jb * 128 + row) << 7) + c16 * 8);
            *(uint4*)(&Bs[row][c16 * 8]) = vb;
        }
        // stage A
        if (jb == 0) {
            #pragma unroll
            for (int i = 0; i < 8; ++i) {
                int c = t + i * 256;
                int row = c >> 4, c16 = c & 15;
                uint4 va = *(const uint4*)(Xb + ((size_t)(m0 + row) << 7) + c16 * 8);
                *(uint4*)(&As[row][c16 * 8]) = va;
            }
        } else {
            int r = jb - 1;
            float f[64];
            #pragma unroll
            for (int k = 0; k < 64; ++k) f[k] = 0.f;
            int nc = ncs[node2];
            int c = 0;
            for (int j = 0; j < nc; ++j) {
                int v = bkc[node2][j];
                if ((v & 15) == r) {
                    ++c;
                    const ushort_t* xr = Xb + (((size_t)(v >> 4)) << 7) + half * 64;
                    #pragma unroll
                    for (int q = 0; q < 8; ++q) {
                        uint4 u = *(const uint4*)(xr + q * 8);
                        f[q * 8 + 0] += __builtin_bit_cast(float, u.x << 16);
                        f[q * 8 + 1] += __builtin_bit_cast(float, u.x & 0xffff0000u);
                        f[q * 8 + 2] += __builtin_bit_cast(float, u.y << 16);
                        f[q * 8 + 3] += __builtin_bit_cast(float, u.y & 0xffff0000u);
                        f[q * 8 + 4] += __builtin_bit_cast(float, u.z << 16);
                        f[q * 8 + 5] += __builtin_bit_cast(float, u.z & 0xffff0000u);
                        f[q * 8 + 6] += __builtin_bit_cast(float, u.w << 16);
                        f[q * 8 + 7] += __builtin_bit_cast(float, u.w & 0xffff0000u);
                    }
                }
            }
            float inv = (c > 0) ? 1.0f / (float)c : 0.0f;
            #pragma unroll
            for (int q = 0; q < 8; ++q) {
                uint4 o;
                o.x = ((unsigned)f2b(f[q * 8 + 1] * inv) << 16) | f2b(f[q * 8 + 0] * inv);
                o.y = ((unsigned)f2b(f[q * 8 + 3] * inv) << 16) | f2b(f[q * 8 + 2] * inv);
                o.z = ((unsigned)f2b(f[q * 8 + 5] * inv) << 16) | f2b(f[q * 8 + 4] * inv);
                o.w = ((unsigned)f2b(f[q * 8 + 7] * inv) << 16) | f2b(f[q * 8 + 6] * inv);
                *(uint4*)(&As[node2][half * 64 + q * 8]) = o;
            }
        }
        __syncthreads();
        // MFMA over K=128 (4 k-steps of 32)
        #pragma unroll
        for (int ks = 0; ks < 4; ++ks) {
            int k0 = ks * 32 + lq * 8;
            bf16x8 a[4], b[4];
            #pragma unroll
            for (int mi = 0; mi < 4; ++mi) a[mi] = *(const bf16x8*)(&As[wm + mi * 16 + lrow][k0]);
            #pragma unroll
            for (int ni = 0; ni < 4; ++ni) b[ni] = *(const bf16x8*)(&Bs[wn + ni * 16 + lrow][k0]);
            #pragma unroll
            for (int mi = 0; mi < 4; ++mi)
                #pragma unroll
                for (int ni = 0; ni < 4; ++ni)
                    acc[mi][ni] = __builtin_amdgcn_mfma_f32_16x16x32_bf16(a[mi], b[ni], acc[mi][ni], 0, 0, 0);
        }
        __syncthreads();
    }

    // epilogue: relu(acc + bias)*linw, reduce over cols, per node row
    float bcol[4], lcol[4];
    #pragma unroll
    for (int ni = 0; ni < 4; ++ni) {
        int col = wn + ni * 16 + lrow;
        bcol[ni] = ldf(bias, col, isbf);
        lcol[ni] = ldf(linw, col, isbf);
    }
    #pragma unroll
    for (int mi = 0; mi < 4; ++mi)
        #pragma unroll
        for (int rg = 0; rg < 4; ++rg) {
            float s = 0.f;
            #pragma unroll
            for (int ni = 0; ni < 4; ++ni)
                s += fmaxf(acc[mi][ni][rg] + bcol[ni], 0.f) * lcol[ni];
            s += __shfl_down(s, 8, 16);
            s += __shfl_down(s, 4, 16);
            s += __shfl_down(s, 2, 16);
            s += __shfl_down(s, 1, 16);
            if (lrow == 0) atomicAdd(&scorebuf[wm + mi * 16 + lq * 4 + rg], s);
        }
    __syncthreads();
    if (t < 128) {
        float res = scorebuf[t] + ldf(linb, 0, isbf);
        if (isbf) ((ushort_t*)out)[m0 + t] = f2b(res);
        else      ((float*)out)[m0 + t] = res;
    }
}

extern "C" void kernel_launch(void* const* d_in, const int* in_sizes, int n_in,
                              void* d_out, int out_size, void* d_ws, size_t ws_size,
                              hipStream_t stream) {
    const void* x     = d_in[0];
    const int*  ei    = (const int*)d_in[1];
    const int*  et    = (const int*)d_in[2];
    const void* relw  = d_in[3];
    const void* rootw = d_in[4];
    const void* bias  = d_in[5];
    const void* linw  = d_in[6];
    const void* linb  = d_in[7];

    const size_t WS_NEED = 16941312;
    if (ws_size < WS_NEED) return;

    char* ws = (char*)d_ws;
    ushort_t* Xb     = (ushort_t*)(ws);                       // 8,388,608
    ushort_t* WT     = (ushort_t*)(ws + 8388608);             // 557,056
    int*      dcnt   = (int*)(ws + 8945664);                  // 131,072
    int*      bucket = (int*)(ws + 9076736);                  // 7,864,320 (32768*60*4)
    int*      flags  = (int*)(ws + 16941056);                 // 256

    hipMemsetAsync(dcnt, 0, 131072, stream);
    pe_k<<<5185, 256, 0, stream>>>(x, relw, rootw, ei, et, Xb, WT, dcnt, bucket, flags);
    rgcn_k<<<256, 256, 0, stream>>>(Xb, WT, dcnt, bucket, bias, linw, linb, d_out, flags);
}

// Round 12
// 178.201 us; speedup vs baseline: 1.8190x; 1.8190x over previous
//
#include <hip/hip_runtime.h>

// Problem constants
#define BB 8
#define NN 4096
#define CC 128
#define RR 16
#define EE 65536
#define NNODES 32768
#define NEDGES 524288
#define KTOT   2176              // 17*128 columns of Y: [root | rel0..rel15]
#define LDP    80                // LDS row stride (shorts): 160B, 16B-aligned/row
#define CSP    136               // epilogue LDS stride: 272B, 16B-aligned/row
#define BCAP   60                // per-dst bucket capacity (Poisson16: P(ovf)~1e-11)
#define GEMMB  4352              // 256 m-tiles * 17 n-tiles

typedef unsigned short ushort_t;
typedef short bf16x8 __attribute__((ext_vector_type(8)));
typedef float f32x4 __attribute__((ext_vector_type(4)));

__device__ __forceinline__ unsigned short f2b(float f) {
    unsigned u = __builtin_bit_cast(unsigned, f);
    unsigned r = (u + 0x7fffu + ((u >> 16) & 1u)) >> 16;   // RNE
    return (unsigned short)r;
}
__device__ __forceinline__ float b2f(unsigned short s) {
    return __builtin_bit_cast(float, (unsigned)s << 16);
}
__device__ __forceinline__ float ldf(const void* p, int j, int isbf) {
    return isbf ? b2f(((const ushort_t*)p)[j]) : ((const float*)p)[j];
}
__device__ __forceinline__ int ldi(const int* p, int j, int is64) {
    return p[j << is64];
}

// wave-parallel float-dtype probe: fp32 mantissa noise shows huge bf16 "exponent"
__device__ __forceinline__ int probe_isbf(const ushort_t* xf) {
    int t = threadIdx.x & 63;
    int bad = 0;
    for (int j = t; j < 512; j += 64) {
        unsigned e = (xf[j] >> 7) & 0xffu;
        if (e >= 160u) bad = 1;
    }
    return __ballot(bad) == 0ull;
}

// ---------- prep_k: casts + dcnt zeroing + flag publication ----------
// [0,2048): cast x->Xb | [2048,3136): weights->WT | [3136,3168): zero dcnt | 3168: flags
__global__ __launch_bounds__(256) void prep_k(const void* __restrict__ x,
                                              const void* __restrict__ relw,
                                              const void* __restrict__ rootw,
                                              const int* __restrict__ ei,
                                              const int* __restrict__ et,
                                              ushort_t* __restrict__ Xb,
                                              ushort_t* __restrict__ WT,
                                              int* __restrict__ dcnt,
                                              int* __restrict__ flags) {
    int bx = blockIdx.x, t = threadIdx.x;
    if (bx < 2048) {                       // cast_x: uint4 group per thread
        int isbf = probe_isbf((const ushort_t*)x);
        int tid = bx * 256 + t;            // < 524288
        if (isbf) {
            ((uint4*)Xb)[tid] = ((const uint4*)x)[tid];
        } else {
            const float4* xf = (const float4*)x;
            float4 a = xf[2 * tid], b = xf[2 * tid + 1];
            ushort4 o0, o1;
            o0.x = f2b(a.x); o0.y = f2b(a.y); o0.z = f2b(a.z); o0.w = f2b(a.w);
            o1.x = f2b(b.x); o1.y = f2b(b.y); o1.z = f2b(b.z); o1.w = f2b(b.w);
            ((ushort4*)Xb)[2 * tid] = o0; ((ushort4*)Xb)[2 * tid + 1] = o1;
        }
    } else if (bx < 3136) {                // cast_w: WT[nglob][k] = Wall[k][nglob]
        int isbf = probe_isbf((const ushort_t*)x);
        int tid = (bx - 2048) * 256 + t;   // < 278528
        int nglob = tid >> 7, k = tid & 127;
        int jb = nglob >> 7, n = nglob & 127;
        float v = (jb == 0) ? ldf(rootw, k * 128 + n, isbf)
                            : ldf(relw, ((jb - 1) << 14) + k * 128 + n, isbf);
        WT[tid] = f2b(v);
    } else if (bx < 3168) {                // zero dcnt (8192 uint4)
        int tid = (bx - 3136) * 256 + t;
        ((uint4*)dcnt)[tid] = make_uint4(0, 0, 0, 0);
    } else {                               // flags
        if (t < 64) {
            int isbf = probe_isbf((const ushort_t*)x);
            int a = (t < 16) ? ei[2 * t + 1] : 0;
            int b = (t < 16) ? et[2 * t + 1] : 0;
            unsigned long long ma = __ballot(a != 0);
            unsigned long long mb = __ballot(b != 0);
            if (t == 0) {
                flags[0] = isbf;
                flags[1] = (ma == 0ull);
                flags[2] = (mb == 0ull);
            }
        }
    }
}

// ---------- ge_k: fused MFMA GEMM + edge bucketing (independent block families) ----------
// blocks [0,GEMMB): Y = Xb @ Wall; [GEMMB, GEMMB+2048): edge append (hides behind MFMA).
// Epilogue routes acc through dead As/Bs LDS -> coalesced uint4 Y stores.
__global__ __launch_bounds__(256) void ge_k(const ushort_t* __restrict__ Xb,
                                            const ushort_t* __restrict__ WT,
                                            ushort_t* __restrict__ Y,
                                            const int* __restrict__ ei,
                                            const int* __restrict__ et,
                                            int* __restrict__ dcnt,
                                            int* __restrict__ bucket,
                                            const int* __restrict__ flags) {
    __shared__ ushort_t smem[2 * 128 * LDP];   // As | Bs; reused as Cs in epilogue
    int bx = blockIdx.x, t = threadIdx.x;
    if (bx >= GEMMB) {                     // ---- edge path: one edge per thread ----
        int w64i = flags[1], w64t = flags[2];
        int tid = (bx - GEMMB) * 256 + t;  // < NEDGES
        int b = tid >> 16, e = tid & 65535;
        int src = ldi(ei, (b * 2) * EE + e, w64i);
        int dst = ldi(ei, (b * 2 + 1) * EE + e, w64i);
        int r = ldi(et, tid, w64t);
        int gd = (b << 12) + dst;
        int pos = atomicAdd(&dcnt[gd], 1);
        if (pos < BCAP)
            bucket[gd * BCAP + pos] = (((b << 12) + src) << 4) | r;
        return;
    }
    // ---- gemm path ----
    ushort_t* As = smem;                   // [128][LDP]
    ushort_t* Bs = smem + 128 * LDP;       // [128][LDP]
    int m0 = (bx & 255) * 128, n0 = (bx >> 8) * 128;
    int wave = t >> 6, lane = t & 63, lrow = lane & 15, lq = lane >> 4;
    int wm = (wave >> 1) * 64, wn = (wave & 1) * 64;
    f32x4 acc[4][4] = {};

    for (int kt = 0; kt < 2; ++kt) {
        #pragma unroll
        for (int i = 0; i < 4; ++i) {
            int c = t + i * 256;
            int row = c >> 3, c8 = c & 7;
            uint4 va = *(const uint4*)(Xb + (size_t)(m0 + row) * 128 + kt * 64 + c8 * 8);
            *(uint4*)(&As[row * LDP + c8 * 8]) = va;
            uint4 vb = *(const uint4*)(WT + (size_t)(n0 + row) * 128 + kt * 64 + c8 * 8);
            *(uint4*)(&Bs[row * LDP + c8 * 8]) = vb;
        }
        __syncthreads();
        #pragma unroll
        for (int ks = 0; ks < 2; ++ks) {
            int k0 = ks * 32 + lq * 8;
            bf16x8 a[4], b[4];
            #pragma unroll
            for (int mi = 0; mi < 4; ++mi) a[mi] = *(const bf16x8*)(&As[(wm + mi * 16 + lrow) * LDP + k0]);
            #pragma unroll
            for (int ni = 0; ni < 4; ++ni) b[ni] = *(const bf16x8*)(&Bs[(wn + ni * 16 + lrow) * LDP + k0]);
            #pragma unroll
            for (int mi = 0; mi < 4; ++mi)
                #pragma unroll
                for (int ni = 0; ni < 4; ++ni)
                    acc[mi][ni] = __builtin_amdgcn_mfma_f32_16x16x32_bf16(a[mi], b[ni], acc[mi][ni], 0, 0, 0);
        }
        __syncthreads();
    }
    // Epilogue: scatter acc (C/D layout col=lane&15, row=quad*4+reg) into LDS Cs,
    // then write Y with coalesced 16B stores. CSP=136 shorts: 272B rows, 16B-aligned.
    ushort_t* Cs = smem;                   // [128][CSP], 17408 shorts <= 20480
    #pragma unroll
    for (int mi = 0; mi < 4; ++mi)
        #pragma unroll
        for (int rg = 0; rg < 4; ++rg) {
            int row = wm + mi * 16 + lq * 4 + rg;
            #pragma unroll
            for (int ni = 0; ni < 4; ++ni)
                Cs[row * CSP + wn + ni * 16 + lrow] = f2b(acc[mi][ni][rg]);
        }
    __syncthreads();
    #pragma unroll
    for (int i = 0; i < 8; ++i) {          // 2048 uint4 chunks, 8 per thread
        int c = t + i * 256;
        int row = c >> 4, c16 = c & 15;
        uint4 v = *(const uint4*)(&Cs[row * CSP + c16 * 8]);
        *(uint4*)(Y + (size_t)(m0 + row) * KTOT + n0 + c16 * 8) = v;
    }
}

// ---------- fused: root + weighted Y gathers (counts from bucket via LDS) + score ----------
__global__ __launch_bounds__(128) void agg_score_k(const ushort_t* __restrict__ Y,
                                                   const int* __restrict__ dcnt,
                                                   const int* __restrict__ bucket,
                                                   const void* __restrict__ bias,
                                                   const void* __restrict__ linw,
                                                   const void* __restrict__ linb,
                                                   void* __restrict__ out,
                                                   const int* __restrict__ flags) {
    int i = blockIdx.x, t = threadIdx.x;
    int isbf = flags[0];
    __shared__ int scnt[RR];
    __shared__ float inv[RR];
    int nc = dcnt[i]; if (nc > BCAP) nc = BCAP;
    const int* bk = bucket + i * BCAP;
    if (t < RR) scnt[t] = 0;
    __syncthreads();
    if (t < nc) atomicAdd(&scnt[bk[t] & 15], 1);   // nc <= 60 < 128
    __syncthreads();
    if (t < RR) inv[t] = (scnt[t] > 0) ? 1.0f / (float)scnt[t] : 0.0f;
    __syncthreads();

    float acc = b2f(Y[(size_t)i * KTOT + t]) + ldf(bias, t, isbf);   // root + bias
    int e = 0;
    for (; e + 7 < nc; e += 8) {           // 8 independent gathers in flight
        int v[8]; float y[8];
        #pragma unroll
        for (int j = 0; j < 8; ++j) v[j] = bk[e + j];
        #pragma unroll
        for (int j = 0; j < 8; ++j)
            y[j] = b2f(Y[(size_t)(v[j] >> 4) * KTOT + CC + ((v[j] & 15) << 7) + t]);
        #pragma unroll
        for (int j = 0; j < 8; ++j) acc += inv[v[j] & 15] * y[j];
    }
    for (; e + 3 < nc; e += 4) {
        int v0 = bk[e], v1 = bk[e + 1], v2 = bk[e + 2], v3 = bk[e + 3];
        float y0 = b2f(Y[(size_t)(v0 >> 4) * KTOT + CC + ((v0 & 15) << 7) + t]);
        float y1 = b2f(Y[(size_t)(v1 >> 4) * KTOT + CC + ((v1 & 15) << 7) + t]);
        float y2 = b2f(Y[(size_t)(v2 >> 4) * KTOT + CC + ((v2 & 15) << 7) + t]);
        float y3 = b2f(Y[(size_t)(v3 >> 4) * KTOT + CC + ((v3 & 15) << 7) + t]);
        acc += inv[v0 & 15] * y0 + inv[v1 & 15] * y1 + inv[v2 & 15] * y2 + inv[v3 & 15] * y3;
    }
    for (; e < nc; ++e) {
        int v = bk[e];
        acc += inv[v & 15] * b2f(Y[(size_t)(v >> 4) * KTOT + CC + ((v & 15) << 7) + t]);
    }
    float val = fmaxf(acc, 0.f) * ldf(linw, t, isbf);
    for (int o = 32; o > 0; o >>= 1) val += __shfl_down(val, o, 64);
    __shared__ float red[2];
    if ((t & 63) == 0) red[t >> 6] = val;
    __syncthreads();
    if (t == 0) {
        float res = red[0] + red[1] + ldf(linb, 0, isbf);
        if (isbf) ((ushort_t*)out)[i] = f2b(res);
        else      ((float*)out)[i] = res;
    }
}

extern "C" void kernel_launch(void* const* d_in, const int* in_sizes, int n_in,
                              void* d_out, int out_size, void* d_ws, size_t ws_size,
                              hipStream_t stream) {
    const void* x     = d_in[0];
    const int*  ei    = (const int*)d_in[1];
    const int*  et    = (const int*)d_in[2];
    const void* relw  = d_in[3];
    const void* rootw = d_in[4];
    const void* bias  = d_in[5];
    const void* linw  = d_in[6];
    const void* linb  = d_in[7];

    const size_t WS_NEED = 159547904;
    if (ws_size < WS_NEED) return;

    char* ws = (char*)d_ws;
    ushort_t* Y      = (ushort_t*)(ws);                       // 142,606,336
    ushort_t* Xb     = (ushort_t*)(ws + 142606336);           // 8,388,608
    ushort_t* WT     = (ushort_t*)(ws + 150994944);           // 557,056
    int*      dcnt   = (int*)(ws + 151552000);                // 131,072
    int*      bucket = (int*)(ws + 151683072);                // 7,864,320 (32768*60*4)
    int*      flags  = (int*)(ws + 159547392);                // 256

    prep_k<<<3169, 256, 0, stream>>>(x, relw, rootw, ei, et, Xb, WT, dcnt, flags);
    ge_k<<<GEMMB + 2048, 256, 0, stream>>>(Xb, WT, Y, ei, et, dcnt, bucket, flags);
    agg_score_k<<<NNODES, 128, 0, stream>>>(Y, dcnt, bucket, bias, linw, linb, d_out, flags);
}

// Round 13
// 167.169 us; speedup vs baseline: 1.9390x; 1.0660x over previous
//
#include <hip/hip_runtime.h>

// Problem constants
#define BB 8
#define NN 4096
#define CC 128
#define RR 16
#define EE 65536
#define NNODES 32768
#define NEDGES 524288
#define KTOT   2176              // 17*128 columns of Y: [root | rel0..rel15]
#define LDP    80                // LDS row stride (shorts): 160B, 16B-aligned/row
#define CSP    136               // epilogue LDS stride: 272B, 16B-aligned/row
#define BCAP   60                // per-dst bucket capacity (Poisson16: P(ovf)~1e-11)
#define GEMMB  4352              // 256 m-tiles * 17 n-tiles
#define EDGEB  2048              // edge-family blocks (dispatched FIRST)

typedef unsigned short ushort_t;
typedef short bf16x8 __attribute__((ext_vector_type(8)));
typedef float f32x4 __attribute__((ext_vector_type(4)));

__device__ __forceinline__ unsigned short f2b(float f) {
    unsigned u = __builtin_bit_cast(unsigned, f);
    unsigned r = (u + 0x7fffu + ((u >> 16) & 1u)) >> 16;   // RNE
    return (unsigned short)r;
}
__device__ __forceinline__ float b2f(unsigned short s) {
    return __builtin_bit_cast(float, (unsigned)s << 16);
}
__device__ __forceinline__ float ldf(const void* p, int j, int isbf) {
    return isbf ? b2f(((const ushort_t*)p)[j]) : ((const float*)p)[j];
}
__device__ __forceinline__ int ldi(const int* p, int j, int is64) {
    return p[j << is64];
}

// wave-parallel float-dtype probe: fp32 mantissa noise shows huge bf16 "exponent"
__device__ __forceinline__ int probe_isbf(const ushort_t* xf) {
    int t = threadIdx.x & 63;
    int bad = 0;
    for (int j = t; j < 512; j += 64) {
        unsigned e = (xf[j] >> 7) & 0xffu;
        if (e >= 160u) bad = 1;
    }
    return __ballot(bad) == 0ull;
}

// ---------- prep_k: casts + dcnt zeroing + flag publication ----------
// [0,2048): cast x->Xb | [2048,3136): weights->WT | [3136,3168): zero dcnt | 3168: flags
__global__ __launch_bounds__(256) void prep_k(const void* __restrict__ x,
                                              const void* __restrict__ relw,
                                              const void* __restrict__ rootw,
                                              const int* __restrict__ ei,
                                              const int* __restrict__ et,
                                              ushort_t* __restrict__ Xb,
                                              ushort_t* __restrict__ WT,
                                              int* __restrict__ dcnt,
                                              int* __restrict__ flags) {
    int bx = blockIdx.x, t = threadIdx.x;
    if (bx < 2048) {                       // cast_x: uint4 group per thread
        int isbf = probe_isbf((const ushort_t*)x);
        int tid = bx * 256 + t;            // < 524288
        if (isbf) {
            ((uint4*)Xb)[tid] = ((const uint4*)x)[tid];
        } else {
            const float4* xf = (const float4*)x;
            float4 a = xf[2 * tid], b = xf[2 * tid + 1];
            ushort4 o0, o1;
            o0.x = f2b(a.x); o0.y = f2b(a.y); o0.z = f2b(a.z); o0.w = f2b(a.w);
            o1.x = f2b(b.x); o1.y = f2b(b.y); o1.z = f2b(b.z); o1.w = f2b(b.w);
            ((ushort4*)Xb)[2 * tid] = o0; ((ushort4*)Xb)[2 * tid + 1] = o1;
        }
    } else if (bx < 3136) {                // cast_w: WT[nglob][k] = Wall[k][nglob]
        int isbf = probe_isbf((const ushort_t*)x);
        int tid = (bx - 2048) * 256 + t;   // < 278528
        int nglob = tid >> 7, k = tid & 127;
        int jb = nglob >> 7, n = nglob & 127;
        float v = (jb == 0) ? ldf(rootw, k * 128 + n, isbf)
                            : ldf(relw, ((jb - 1) << 14) + k * 128 + n, isbf);
        WT[tid] = f2b(v);
    } else if (bx < 3168) {                // zero dcnt (8192 uint4)
        int tid = (bx - 3136) * 256 + t;
        ((uint4*)dcnt)[tid] = make_uint4(0, 0, 0, 0);
    } else {                               // flags
        if (t < 64) {
            int isbf = probe_isbf((const ushort_t*)x);
            int a = (t < 16) ? ei[2 * t + 1] : 0;
            int b = (t < 16) ? et[2 * t + 1] : 0;
            unsigned long long ma = __ballot(a != 0);
            unsigned long long mb = __ballot(b != 0);
            if (t == 0) {
                flags[0] = isbf;
                flags[1] = (ma == 0ull);
                flags[2] = (mb == 0ull);
            }
        }
    }
}

// ---------- ge_k: fused edge bucketing (FIRST) + MFMA GEMM ----------
// blocks [0,EDGEB): edge append — dispatched first so atomic latency spans the
// whole kernel instead of forming a tail; [EDGEB, EDGEB+GEMMB): Y = Xb @ Wall.
__global__ __launch_bounds__(256) void ge_k(const ushort_t* __restrict__ Xb,
                                            const ushort_t* __restrict__ WT,
                                            ushort_t* __restrict__ Y,
                                            const int* __restrict__ ei,
                                            const int* __restrict__ et,
                                            int* __restrict__ dcnt,
                                            int* __restrict__ bucket,
                                            const int* __restrict__ flags) {
    __shared__ ushort_t smem[2 * 128 * LDP];   // As | Bs; reused as Cs in epilogue
    int bx = blockIdx.x, t = threadIdx.x;
    if (bx < EDGEB) {                      // ---- edge path: one edge per thread ----
        int w64i = flags[1], w64t = flags[2];
        int tid = bx * 256 + t;            // < NEDGES
        int b = tid >> 16, e = tid & 65535;
        int src = ldi(ei, (b * 2) * EE + e, w64i);
        int dst = ldi(ei, (b * 2 + 1) * EE + e, w64i);
        int r = ldi(et, tid, w64t);
        int gd = (b << 12) + dst;
        int pos = atomicAdd(&dcnt[gd], 1);
        if (pos < BCAP)
            bucket[gd * BCAP + pos] = (((b << 12) + src) << 4) | r;
        return;
    }
    // ---- gemm path ----
    int bxg = bx - EDGEB;
    ushort_t* As = smem;                   // [128][LDP]
    ushort_t* Bs = smem + 128 * LDP;       // [128][LDP]
    int m0 = (bxg & 255) * 128, n0 = (bxg >> 8) * 128;
    int wave = t >> 6, lane = t & 63, lrow = lane & 15, lq = lane >> 4;
    int wm = (wave >> 1) * 64, wn = (wave & 1) * 64;
    f32x4 acc[4][4] = {};

    for (int kt = 0; kt < 2; ++kt) {
        #pragma unroll
        for (int i = 0; i < 4; ++i) {
            int c = t + i * 256;
            int row = c >> 3, c8 = c & 7;
            uint4 va = *(const uint4*)(Xb + (size_t)(m0 + row) * 128 + kt * 64 + c8 * 8);
            *(uint4*)(&As[row * LDP + c8 * 8]) = va;
            uint4 vb = *(const uint4*)(WT + (size_t)(n0 + row) * 128 + kt * 64 + c8 * 8);
            *(uint4*)(&Bs[row * LDP + c8 * 8]) = vb;
        }
        __syncthreads();
        #pragma unroll
        for (int ks = 0; ks < 2; ++ks) {
            int k0 = ks * 32 + lq * 8;
            bf16x8 a[4], b[4];
            #pragma unroll
            for (int mi = 0; mi < 4; ++mi) a[mi] = *(const bf16x8*)(&As[(wm + mi * 16 + lrow) * LDP + k0]);
            #pragma unroll
            for (int ni = 0; ni < 4; ++ni) b[ni] = *(const bf16x8*)(&Bs[(wn + ni * 16 + lrow) * LDP + k0]);
            #pragma unroll
            for (int mi = 0; mi < 4; ++mi)
                #pragma unroll
                for (int ni = 0; ni < 4; ++ni)
                    acc[mi][ni] = __builtin_amdgcn_mfma_f32_16x16x32_bf16(a[mi], b[ni], acc[mi][ni], 0, 0, 0);
        }
        __syncthreads();
    }
    // Epilogue via LDS -> coalesced uint4 stores (R12-verified)
    ushort_t* Cs = smem;                   // [128][CSP]
    #pragma unroll
    for (int mi = 0; mi < 4; ++mi)
        #pragma unroll
        for (int rg = 0; rg < 4; ++rg) {
            int row = wm + mi * 16 + lq * 4 + rg;
            #pragma unroll
            for (int ni = 0; ni < 4; ++ni)
                Cs[row * CSP + wn + ni * 16 + lrow] = f2b(acc[mi][ni][rg]);
        }
    __syncthreads();
    #pragma unroll
    for (int i = 0; i < 8; ++i) {
        int c = t + i * 256;
        int row = c >> 4, c16 = c & 15;
        uint4 v = *(const uint4*)(&Cs[row * CSP + c16 * 8]);
        *(uint4*)(Y + (size_t)(m0 + row) * KTOT + n0 + c16 * 8) = v;
    }
}

// ---------- agg: group-gather (16 lanes x uint4 = full 256B row per group) ----------
// 128 threads = 8 groups; group g gathers edges e = base+g. Per-thread 8-col
// partials reduce via part[128][9] LDS (pad 9 -> max 4-way bank conflict).
__global__ __launch_bounds__(128) void agg_score_k(const ushort_t* __restrict__ Y,
                                                   const int* __restrict__ dcnt,
                                                   const int* __restrict__ bucket,
                                                   const void* __restrict__ bias,
                                                   const void* __restrict__ linw,
                                                   const void* __restrict__ linb,
                                                   void* __restrict__ out,
                                                   const int* __restrict__ flags) {
    int i = blockIdx.x, t = threadIdx.x;
    int isbf = flags[0];
    __shared__ int scnt[RR];
    __shared__ float inv[RR];
    __shared__ int bke[64];
    __shared__ float part[128][9];
    int nc = dcnt[i]; if (nc > BCAP) nc = BCAP;
    const int* bk = bucket + i * BCAP;
    if (t < RR) scnt[t] = 0;
    __syncthreads();
    if (t < nc) { int v = bk[t]; bke[t] = v; atomicAdd(&scnt[v & 15], 1); }
    __syncthreads();
    if (t < RR) inv[t] = (scnt[t] > 0) ? 1.0f / (float)scnt[t] : 0.0f;
    __syncthreads();

    int g = t >> 4, l16 = t & 15;          // group, lane-in-group
    float a8[8] = {};
    for (int base = 0; base < nc; base += 8) {
        int e = base + g;
        if (e < nc) {
            int v = bke[e];
            const ushort_t* yr = Y + (size_t)(v >> 4) * KTOT + CC + ((v & 15) << 7) + l16 * 8;
            uint4 u = *(const uint4*)yr;
            float w = inv[v & 15];
            a8[0] += w * __builtin_bit_cast(float, u.x << 16);
            a8[1] += w * __builtin_bit_cast(float, u.x & 0xffff0000u);
            a8[2] += w * __builtin_bit_cast(float, u.y << 16);
            a8[3] += w * __builtin_bit_cast(float, u.y & 0xffff0000u);
            a8[4] += w * __builtin_bit_cast(float, u.z << 16);
            a8[5] += w * __builtin_bit_cast(float, u.z & 0xffff0000u);
            a8[6] += w * __builtin_bit_cast(float, u.w << 16);
            a8[7] += w * __builtin_bit_cast(float, u.w & 0xffff0000u);
        }
    }
    #pragma unroll
    for (int j = 0; j < 8; ++j) part[l16 * 8 + j][g] = a8[j];
    __syncthreads();

    // col t: sum 8 group partials + root + bias, relu, * linw, reduce
    float acc = b2f(Y[(size_t)i * KTOT + t]) + ldf(bias, t, isbf);
    #pragma unroll
    for (int gg = 0; gg < 8; ++gg) acc += part[t][gg];
    float val = fmaxf(acc, 0.f) * ldf(linw, t, isbf);
    for (int o = 32; o > 0; o >>= 1) val += __shfl_down(val, o, 64);
    __shared__ float red[2];
    if ((t & 63) == 0) red[t >> 6] = val;
    __syncthreads();
    if (t == 0) {
        float res = red[0] + red[1] + ldf(linb, 0, isbf);
        if (isbf) ((ushort_t*)out)[i] = f2b(res);
        else      ((float*)out)[i] = res;
    }
}

extern "C" void kernel_launch(void* const* d_in, const int* in_sizes, int n_in,
                              void* d_out, int out_size, void* d_ws, size_t ws_size,
                              hipStream_t stream) {
    const void* x     = d_in[0];
    const int*  ei    = (const int*)d_in[1];
    const int*  et    = (const int*)d_in[2];
    const void* relw  = d_in[3];
    const void* rootw = d_in[4];
    const void* bias  = d_in[5];
    const void* linw  = d_in[6];
    const void* linb  = d_in[7];

    const size_t WS_NEED = 159547904;
    if (ws_size < WS_NEED) return;

    char* ws = (char*)d_ws;
    ushort_t* Y      = (ushort_t*)(ws);                       // 142,606,336
    ushort_t* Xb     = (ushort_t*)(ws + 142606336);           // 8,388,608
    ushort_t* WT     = (ushort_t*)(ws + 150994944);           // 557,056
    int*      dcnt   = (int*)(ws + 151552000);                // 131,072
    int*      bucket = (int*)(ws + 151683072);                // 7,864,320 (32768*60*4)
    int*      flags  = (int*)(ws + 159547392);                // 256

    prep_k<<<3169, 256, 0, stream>>>(x, relw, rootw, ei, et, Xb, WT, dcnt, flags);
    ge_k<<<EDGEB + GEMMB, 256, 0, stream>>>(Xb, WT, Y, ei, et, dcnt, bucket, flags);
    agg_score_k<<<NNODES, 128, 0, stream>>>(Y, dcnt, bucket, bias, linw, linb, d_out, flags);
}